// Round 2
// baseline (344.222 us; speedup 1.0000x reference)
//
#include <hip/hip_runtime.h>
#include <hip/hip_bf16.h>

// Problem constants
#define NN 20000
#define NG 1250                  // node groups of 16
#define NB 625                   // lstm blocks: 2 groups per block (per wave)
#define LOG2E 1.44269504088896f
#define TWOLOG2E 2.88539008177793f
#define SORT_BLOCKS 79           // 79*256 = 20224 >= 20000
#define PREP_BLOCKS 1024

typedef __attribute__((ext_vector_type(8))) short short8;   // 8 bf16 = 4 VGPRs (MFMA A/B frag)
typedef __attribute__((ext_vector_type(4))) float floatx4;  // MFMA C/D frag

__device__ __forceinline__ floatx4 MF(short8 a, short8 b, floatx4 c) {
    return __builtin_amdgcn_mfma_f32_16x16x32_bf16(a, b, c, 0, 0, 0);
}
__device__ __forceinline__ float ex2(float x) { return __builtin_amdgcn_exp2f(x); }
__device__ __forceinline__ float rcp(float x) { return __builtin_amdgcn_rcpf(x); }
__device__ __forceinline__ unsigned short bf16r(float x) {
    return __builtin_bit_cast(unsigned short, __float2bfloat16(x));
}
// barrier that waits ONLY lgkmcnt (LDS) — global prefetch stays in flight.
__device__ __forceinline__ void lds_barrier() {
    asm volatile("s_waitcnt lgkmcnt(0)\n\ts_barrier" ::: "memory");
}
// bank-conflict row swizzle for the h transpose tile (writer+reader must agree)
__device__ __forceinline__ int rowswz(int L) {
    return L ^ (((L >> 4) & 1) << 1) ^ ((L >> 3) & 1);
}

// ---------- fused prep + neighbor sort (one launch; sort latency hides under prep) ----------
#define PREP_TOT (49152 + 49152 + 12288 + 12288 + 768 + 640000)
__global__ void prep_sort_kernel(const float* __restrict__ x,
    const int* __restrict__ nbr, int* __restrict__ nbrT,
    const float* __restrict__ Wih0, const float* __restrict__ Whh0,
    const float* __restrict__ bih0, const float* __restrict__ bhh0, const float* __restrict__ Wl0,
    const float* __restrict__ Wih1, const float* __restrict__ Whh1,
    const float* __restrict__ bih1, const float* __restrict__ bhh1, const float* __restrict__ Wl1,
    const float* __restrict__ Wih2, const float* __restrict__ Whh2,
    const float* __restrict__ bih2, const float* __restrict__ bhh2, const float* __restrict__ Wl2,
    unsigned short* __restrict__ Wih_p, unsigned short* __restrict__ Whh_p,
    unsigned short* __restrict__ Wlx_p, unsigned short* __restrict__ Wlh_p,
    float* __restrict__ bsum, unsigned short* __restrict__ x32)
{
    if (blockIdx.x < SORT_BLOCKS) {
        // ---- sort each node's 32 neighbors ascending; store transposed per 16-node group ----
        int n = blockIdx.x * 256 + threadIdx.x;
        if (n >= NN) return;
        int v[32];
        const int4* src = (const int4*)(nbr + n * 32);
        #pragma unroll
        for (int i = 0; i < 8; i++) {
            int4 t = src[i];
            v[4*i] = t.x; v[4*i+1] = t.y; v[4*i+2] = t.z; v[4*i+3] = t.w;
        }
        #pragma unroll
        for (int k = 2; k <= 32; k <<= 1)
            #pragma unroll
            for (int j = k >> 1; j > 0; j >>= 1)
                #pragma unroll
                for (int i = 0; i < 32; i++) {
                    int ixj = i ^ j;
                    if (ixj > i) {
                        bool up = (i & k) == 0;
                        int a = v[i], b = v[ixj];
                        bool sw = up ? (a > b) : (a < b);
                        if (sw) { v[i] = b; v[ixj] = a; }
                    }
                }
        int g = n >> 4, m = n & 15;
        int base = g * 512 + m;      // nbrT[g][t][m]
        #pragma unroll
        for (int t = 0; t < 32; t++) nbrT[base + t * 16] = v[t];
        return;
    }

    // ---- prep: bf16 weight repack (log2e pre-folded), bias sums, padded x ----
    for (int i = (blockIdx.x - SORT_BLOCKS) * 256 + threadIdx.x; i < PREP_TOT;
         i += PREP_BLOCKS * 256) {
        int j = i;
        if (j < 49152) {                       // Wih_p: [col][k], layer0 K=32 padded from 3
            int l = j >> 14, e = j & 16383;
            if (l == 0) {
                if (e < 8192) {
                    int col = e >> 5, k = e & 31;
                    float sc = (col >= 128 && col < 192) ? TWOLOG2E : LOG2E;
                    float v = (k < 3) ? Wih0[col*3 + k] * sc : 0.f;
                    Wih_p[e] = bf16r(v);
                }
            } else {
                int col = e >> 6, k = e & 63;
                const float* W = (l == 1) ? Wih1 : Wih2;
                float sc = (col >= 128 && col < 192) ? TWOLOG2E : LOG2E;
                Wih_p[l*16384 + e] = bf16r(W[col*64 + k] * sc);
            }
            continue;
        }
        j -= 49152;
        if (j < 49152) {                       // Whh_p
            int l = j >> 14, e = j & 16383;
            int col = e >> 6, k = e & 63;
            const float* W = (l == 0) ? Whh0 : ((l == 1) ? Whh1 : Whh2);
            float sc = (col >= 128 && col < 192) ? TWOLOG2E : LOG2E;
            Whh_p[l*16384 + e] = bf16r(W[col*64 + k] * sc);
            continue;
        }
        j -= 49152;
        if (j < 12288) {                       // Wlx_p, layer0 K=32 padded from 3
            int l = j >> 12, e = j & 4095;
            if (l == 0) {
                if (e < 2048) {
                    int col = e >> 5, k = e & 31;
                    float v = (k < 3) ? Wl0[col*67 + k] : 0.f;
                    Wlx_p[e] = bf16r(v);
                }
            } else {
                int col = e >> 6, k = e & 63;
                const float* W = (l == 1) ? Wl1 : Wl2;
                Wlx_p[l*4096 + e] = bf16r(W[col*128 + k]);
            }
            continue;
        }
        j -= 12288;
        if (j < 12288) {                       // Wlh_p
            int l = j >> 12, e = j & 4095;
            int col = e >> 6, k = e & 63;
            float v = (l == 0) ? Wl0[col*67 + 3 + k]
                               : ((l == 1) ? Wl1 : Wl2)[col*128 + 64 + k];
            Wlh_p[l*4096 + e] = bf16r(v);
            continue;
        }
        j -= 12288;
        if (j < 768) {                         // bsum = (b_ih + b_hh) * scale
            int l = j >> 8, col = j & 255;
            const float* bi = (l == 0) ? bih0 : ((l == 1) ? bih1 : bih2);
            const float* bh = (l == 0) ? bhh0 : ((l == 1) ? bhh1 : bhh2);
            float sc = (col >= 128 && col < 192) ? TWOLOG2E : LOG2E;
            bsum[l*256 + col] = (bi[col] + bh[col]) * sc;
            continue;
        }
        j -= 768;
        {                                      // x32: padded bf16 node features [n][32]
            int n = j >> 5, k = j & 31;
            x32[j] = bf16r((k < 3) ? x[n*3 + k] : 0.f);
        }
    }
}

// ---------- fused LSTM-aggregate + combine (+head), MFMA version ----------
// 4 waves/block, TWO 16-node groups per block. Wave w owns units [16w,16w+16) with ALL
// four gate tiles for BOTH groups -> the weight fragments (the dominant VGPR cost) are
// shared between groups; per-group state (acc/xg/hA/cst) doubles, giving 2 independent
// recurrence chains per wave (8 independent pointwise cells/lane) to hide trans/MFMA
// latency. Only cross-wave sync: h transpose via double-buffered sA, one lgkm-only
// barrier/step covering both groups.
// __launch_bounds__(256, 2): 256-VGPR budget. (256,3) capped at ~170 unified VGPR+AGPR
// and spilled ~5MB/dispatch to scratch (round-1 regression: WRITE_SIZE 2500->5078 KB).
// Achieved residency was ~2 blocks/CU anyway, so the relaxed bound costs nothing.
template<int XKC, int LASTL>
__global__ __launch_bounds__(256, 2)
void lstm_mfma_kernel(const unsigned short* __restrict__ xsrc,  // bf16 rows, stride XKC*32 shorts
                      const int* __restrict__ nbrT,
                      const unsigned short* __restrict__ Wih,   // bf16 [256][XKC*32]
                      const unsigned short* __restrict__ Whh,   // bf16 [256][64]
                      const float* __restrict__ bsum,           // [256] prescaled
                      const unsigned short* __restrict__ Wlx,   // bf16 [64][XKC*32]
                      const unsigned short* __restrict__ Wlh,   // bf16 [64][64]
                      const float* __restrict__ bl,             // [64]
                      const float* __restrict__ W_out,          // [64] (LASTL only)
                      const float* __restrict__ b_out,          // [1]  (LASTL only)
                      void* __restrict__ hout)                  // bf16[n][64] or float[n] (LASTL)
{
    __shared__ unsigned short sA[2][2][1024];   // [group][dbuf] h transpose (swizzled rows)
    __shared__ float sRed[2][64];               // head partial sums (LASTL)

    const int w    = threadIdx.x >> 6;       // 0..3
    const int lane = threadIdx.x & 63;
    const int q    = lane >> 4;
    const int c    = lane & 15;
    const int XS   = XKC * 32;

    const int g0 = blockIdx.x * 2;
    const int node0[2] = { g0 * 16, g0 * 16 + 16 };
    const int* nbg[2]  = { nbrT + g0 * 512, nbrT + g0 * 512 + 512 };

    // persistent weight fragments: tile t4 = gate, col = 64*t4 + 16w + c, k = 32kc+8q+j
    short8 fWih[4][XKC];
    short8 fWhh[4][2];
    float  biasv[4];
    #pragma unroll
    for (int t4 = 0; t4 < 4; t4++) {
        int col = 64*t4 + 16*w + c;
        biasv[t4] = bsum[col];
        #pragma unroll
        for (int kc = 0; kc < XKC; kc++)
            fWih[t4][kc] = *(const short8*)(Wih + col*XS + kc*32 + q*8);
        #pragma unroll
        for (int kc = 0; kc < 2; kc++)
            fWhh[t4][kc] = *(const short8*)(Whh + col*64 + kc*32 + q*8);
    }

    float cst[2][4] = {};
    short8 hA[2][2] = {};

    int idx_nxt[2];
    short8 xg[2][XKC];
    #pragma unroll
    for (int gi = 0; gi < 2; gi++) {
        int ic = nbg[gi][c];
        idx_nxt[gi] = nbg[gi][16 + c];
        #pragma unroll
        for (int kc = 0; kc < XKC; kc++)
            xg[gi][kc] = *(const short8*)(xsrc + (long)ic * XS + kc*32 + q*8);
    }

    #pragma unroll 1
    for (int t = 0; t < 32; t++) {
        floatx4 acc[2][4];
        #pragma unroll
        for (int gi = 0; gi < 2; gi++)
            #pragma unroll
            for (int t4 = 0; t4 < 4; t4++) {
                floatx4 a; a[0] = biasv[t4]; a[1] = biasv[t4]; a[2] = biasv[t4]; a[3] = biasv[t4];
                acc[gi][t4] = a;
            }
        if (t > 0) {
            #pragma unroll
            for (int t4 = 0; t4 < 4; t4++)
                #pragma unroll
                for (int gi = 0; gi < 2; gi++) {
                    acc[gi][t4] = MF(hA[gi][0], fWhh[t4][0], acc[gi][t4]);
                    acc[gi][t4] = MF(hA[gi][1], fWhh[t4][1], acc[gi][t4]);
                }
        }
        #pragma unroll
        for (int t4 = 0; t4 < 4; t4++)
            #pragma unroll
            for (int gi = 0; gi < 2; gi++)
                #pragma unroll
                for (int kc = 0; kc < XKC; kc++)
                    acc[gi][t4] = MF(xg[gi][kc], fWih[t4][kc], acc[gi][t4]);

        // prefetch next step's gathered rows (stays in flight across the lgkm-only barrier)
        if (t < 31) {
            int tn = (t + 2 < 32) ? t + 2 : 31;
            #pragma unroll
            for (int gi = 0; gi < 2; gi++) {
                #pragma unroll
                for (int kc = 0; kc < XKC; kc++)
                    xg[gi][kc] = *(const short8*)(xsrc + (long)idx_nxt[gi] * XS + kc*32 + q*8);
                idx_nxt[gi] = nbg[gi][tn*16 + c];
            }
        }

        // pointwise LSTM cell x2 groups; lane cells: node m=4q+r, unit u=16w+c
        const int u = 16*w + c;
        #pragma unroll
        for (int gi = 0; gi < 2; gi++) {
            unsigned short* sAb = &sA[gi][t & 1][0];
            #pragma unroll
            for (int r = 0; r < 4; r++) {
                float gv = acc[gi][0][r], gf = acc[gi][1][r], gg = acc[gi][2][r], go = acc[gi][3][r];
                float ei = ex2(-gv);
                float ef = ex2(-gf);
                float eo = ex2(-go);
                float eg = ex2(-__builtin_fabsf(gg));
                float iG = __builtin_copysignf(1.f - eg, gg) * rcp((1.f + ei) * (1.f + eg));
                float cm = fmaf(cst[gi][r], rcp(1.f + ef), iG);
                cst[gi][r] = cm;
                float ec = ex2(-TWOLOG2E * __builtin_fabsf(cm));
                float h  = __builtin_copysignf(1.f - ec, cm) * rcp((1.f + eo) * (1.f + ec));
                int row = (4*q + r) + 16*(u >> 3);
                sAb[rowswz(row)*8 + (u & 7)] = bf16r(h);
            }
        }
        lds_barrier();
        #pragma unroll
        for (int gi = 0; gi < 2; gi++) {
            hA[gi][0] = *(const short8*)(&sA[gi][t & 1][0] + rowswz(lane)*8);
            hA[gi][1] = *(const short8*)(&sA[gi][t & 1][0] + 512 + rowswz(lane)*8);
        }
    }

    // ---- combine: relu([h_in, agg] @ Wl^T + bl); agg frags = hA (final h) ----
    const int col = 16*w + c;
    short8 fx[XKC], fh[2];
    float blv = bl[col];
    #pragma unroll
    for (int kc = 0; kc < XKC; kc++)
        fx[kc] = *(const short8*)(Wlx + col*XS + kc*32 + q*8);
    fh[0] = *(const short8*)(Wlh + col*64 + q*8);
    fh[1] = *(const short8*)(Wlh + col*64 + 32 + q*8);

    #pragma unroll
    for (int gi = 0; gi < 2; gi++) {
        short8 hin[XKC];
        #pragma unroll
        for (int kc = 0; kc < XKC; kc++)
            hin[kc] = *(const short8*)(xsrc + (long)(node0[gi] + c) * XS + kc*32 + q*8);

        floatx4 a; a[0] = blv; a[1] = blv; a[2] = blv; a[3] = blv;
        #pragma unroll
        for (int kc = 0; kc < XKC; kc++) a = MF(hin[kc], fx[kc], a);
        a = MF(hA[gi][0], fh[0], a);
        a = MF(hA[gi][1], fh[1], a);

        if (!LASTL) {
            #pragma unroll
            for (int r = 0; r < 4; r++)
                ((unsigned short*)hout)[(node0[gi] + 4*q + r) * 64 + col] = bf16r(fmaxf(a[r], 0.f));
        } else {
            // fused head: out[n] = sum_u relu_comb[n][u] * W_out[u] + b_out
            float wo = W_out[col];
            float p[4];
            #pragma unroll
            for (int r = 0; r < 4; r++) p[r] = fmaxf(a[r], 0.f) * wo;
            #pragma unroll
            for (int d = 1; d < 16; d <<= 1) {
                #pragma unroll
                for (int r = 0; r < 4; r++) p[r] += __shfl_xor(p[r], d);
            }
            if (c == 0) {
                #pragma unroll
                for (int r = 0; r < 4; r++) sRed[gi][w*16 + 4*q + r] = p[r];
            }
        }
    }
    if (LASTL) {
        lds_barrier();
        if (w < 2 && lane < 16)
            ((float*)hout)[node0[w] + lane] =
                sRed[w][lane] + sRed[w][16 + lane] + sRed[w][32 + lane] + sRed[w][48 + lane]
                + b_out[0];
    }
}

extern "C" void kernel_launch(void* const* d_in, const int* in_sizes, int n_in,
                              void* d_out, int out_size, void* d_ws, size_t ws_size,
                              hipStream_t stream) {
    (void)in_sizes; (void)n_in; (void)out_size; (void)ws_size;
    const float* node_features = (const float*)d_in[0];
    const int*   nbr           = (const int*)d_in[1];
    const float* Wih[3] = {(const float*)d_in[2],  (const float*)d_in[8],  (const float*)d_in[14]};
    const float* Whh[3] = {(const float*)d_in[3],  (const float*)d_in[9],  (const float*)d_in[15]};
    const float* bih[3] = {(const float*)d_in[4],  (const float*)d_in[10], (const float*)d_in[16]};
    const float* bhh[3] = {(const float*)d_in[5],  (const float*)d_in[11], (const float*)d_in[17]};
    const float* Wl[3]  = {(const float*)d_in[6],  (const float*)d_in[12], (const float*)d_in[18]};
    const float* bl[3]  = {(const float*)d_in[7],  (const float*)d_in[13], (const float*)d_in[19]};
    const float* W_out  = (const float*)d_in[20];
    const float* b_out  = (const float*)d_in[21];

    char* ws = (char*)d_ws;
    int*            nbrT  = (int*)ws;                               // 2,560,000 B
    unsigned short* x32   = (unsigned short*)(ws + 2560000);        // 1,280,000 B
    unsigned short* hb1   = (unsigned short*)(ws + 3840000);        // 2,560,000 B
    unsigned short* hb2   = (unsigned short*)(ws + 6400000);        // 2,560,000 B
    unsigned short* Wih_p = (unsigned short*)(ws + 8960000);        // 98,304 B
    unsigned short* Whh_p = (unsigned short*)(ws + 9058304);        // 98,304 B
    unsigned short* Wlx_p = (unsigned short*)(ws + 9156608);        // 24,576 B
    unsigned short* Wlh_p = (unsigned short*)(ws + 9181184);        // 24,576 B
    float*          bsum  = (float*)(ws + 9205760);                 // 3,072 B

    prep_sort_kernel<<<SORT_BLOCKS + PREP_BLOCKS, 256, 0, stream>>>(node_features,
        nbr, nbrT,
        Wih[0], Whh[0], bih[0], bhh[0], Wl[0],
        Wih[1], Whh[1], bih[1], bhh[1], Wl[1],
        Wih[2], Whh[2], bih[2], bhh[2], Wl[2],
        Wih_p, Whh_p, Wlx_p, Wlh_p, bsum, x32);

    lstm_mfma_kernel<1, 0><<<NB, 256, 0, stream>>>(x32, nbrT,
        Wih_p,         Whh_p,         bsum,       Wlx_p,        Wlh_p,        bl[0],
        nullptr, nullptr, hb1);
    lstm_mfma_kernel<2, 0><<<NB, 256, 0, stream>>>(hb1, nbrT,
        Wih_p + 16384, Whh_p + 16384, bsum + 256, Wlx_p + 4096, Wlh_p + 4096, bl[1],
        nullptr, nullptr, hb2);
    lstm_mfma_kernel<2, 1><<<NB, 256, 0, stream>>>(hb2, nbrT,
        Wih_p + 32768, Whh_p + 32768, bsum + 512, Wlx_p + 8192, Wlh_p + 8192, bl[2],
        W_out, b_out, (float*)d_out);
}

// Round 3
// 294.149 us; speedup vs baseline: 1.1702x; 1.1702x over previous
//
#include <hip/hip_runtime.h>
#include <hip/hip_bf16.h>

// Problem constants
#define NN 20000
#define NG 1250                  // node groups of 16, one per block (round-0 geometry)
#define LOG2E 1.44269504088896f
#define TWOLOG2E 2.88539008177793f
#define SORT_BLOCKS 79           // 79*256 = 20224 >= 20000
#define PREP_BLOCKS 1024

typedef __attribute__((ext_vector_type(8))) short short8;   // 8 bf16 = 4 VGPRs (MFMA A/B frag)
typedef __attribute__((ext_vector_type(4))) float floatx4;  // MFMA C/D frag

__device__ __forceinline__ floatx4 MF(short8 a, short8 b, floatx4 c) {
    return __builtin_amdgcn_mfma_f32_16x16x32_bf16(a, b, c, 0, 0, 0);
}
__device__ __forceinline__ float ex2(float x) { return __builtin_amdgcn_exp2f(x); }
__device__ __forceinline__ float rcp(float x) { return __builtin_amdgcn_rcpf(x); }
__device__ __forceinline__ unsigned short bf16r(float x) {
    return __builtin_bit_cast(unsigned short, __float2bfloat16(x));
}
// barrier that waits ONLY lgkmcnt (LDS) — global prefetch stays in flight.
__device__ __forceinline__ void lds_barrier() {
    asm volatile("s_waitcnt lgkmcnt(0)\n\ts_barrier" ::: "memory");
}
// bank-conflict row swizzle for the h transpose tile (writer+reader must agree)
__device__ __forceinline__ int rowswz(int L) {
    return L ^ (((L >> 4) & 1) << 1) ^ ((L >> 3) & 1);
}

// ---------- fused prep + neighbor sort (one launch; sort latency hides under prep) ----------
#define PREP_TOT (49152 + 49152 + 12288 + 12288 + 768 + 640000)
__global__ void prep_sort_kernel(const float* __restrict__ x,
    const int* __restrict__ nbr, int* __restrict__ nbrT,
    const float* __restrict__ Wih0, const float* __restrict__ Whh0,
    const float* __restrict__ bih0, const float* __restrict__ bhh0, const float* __restrict__ Wl0,
    const float* __restrict__ Wih1, const float* __restrict__ Whh1,
    const float* __restrict__ bih1, const float* __restrict__ bhh1, const float* __restrict__ Wl1,
    const float* __restrict__ Wih2, const float* __restrict__ Whh2,
    const float* __restrict__ bih2, const float* __restrict__ bhh2, const float* __restrict__ Wl2,
    unsigned short* __restrict__ Wih_p, unsigned short* __restrict__ Whh_p,
    unsigned short* __restrict__ Wlx_p, unsigned short* __restrict__ Wlh_p,
    float* __restrict__ bsum, unsigned short* __restrict__ x32)
{
    if (blockIdx.x < SORT_BLOCKS) {
        // ---- sort each node's 32 neighbors ascending; store transposed per 16-node group ----
        int n = blockIdx.x * 256 + threadIdx.x;
        if (n >= NN) return;
        int v[32];
        const int4* src = (const int4*)(nbr + n * 32);
        #pragma unroll
        for (int i = 0; i < 8; i++) {
            int4 t = src[i];
            v[4*i] = t.x; v[4*i+1] = t.y; v[4*i+2] = t.z; v[4*i+3] = t.w;
        }
        #pragma unroll
        for (int k = 2; k <= 32; k <<= 1)
            #pragma unroll
            for (int j = k >> 1; j > 0; j >>= 1)
                #pragma unroll
                for (int i = 0; i < 32; i++) {
                    int ixj = i ^ j;
                    if (ixj > i) {
                        bool up = (i & k) == 0;
                        int a = v[i], b = v[ixj];
                        bool sw = up ? (a > b) : (a < b);
                        if (sw) { v[i] = b; v[ixj] = a; }
                    }
                }
        int g = n >> 4, m = n & 15;
        int base = g * 512 + m;      // nbrT[g][t][m]
        #pragma unroll
        for (int t = 0; t < 32; t++) nbrT[base + t * 16] = v[t];
        return;
    }

    // ---- prep: bf16 weight repack (log2e pre-folded), bias sums, padded x ----
    for (int i = (blockIdx.x - SORT_BLOCKS) * 256 + threadIdx.x; i < PREP_TOT;
         i += PREP_BLOCKS * 256) {
        int j = i;
        if (j < 49152) {                       // Wih_p: [col][k], layer0 K=32 padded from 3
            int l = j >> 14, e = j & 16383;
            if (l == 0) {
                if (e < 8192) {
                    int col = e >> 5, k = e & 31;
                    float sc = (col >= 128 && col < 192) ? TWOLOG2E : LOG2E;
                    float v = (k < 3) ? Wih0[col*3 + k] * sc : 0.f;
                    Wih_p[e] = bf16r(v);
                }
            } else {
                int col = e >> 6, k = e & 63;
                const float* W = (l == 1) ? Wih1 : Wih2;
                float sc = (col >= 128 && col < 192) ? TWOLOG2E : LOG2E;
                Wih_p[l*16384 + e] = bf16r(W[col*64 + k] * sc);
            }
            continue;
        }
        j -= 49152;
        if (j < 49152) {                       // Whh_p
            int l = j >> 14, e = j & 16383;
            int col = e >> 6, k = e & 63;
            const float* W = (l == 0) ? Whh0 : ((l == 1) ? Whh1 : Whh2);
            float sc = (col >= 128 && col < 192) ? TWOLOG2E : LOG2E;
            Whh_p[l*16384 + e] = bf16r(W[col*64 + k] * sc);
            continue;
        }
        j -= 49152;
        if (j < 12288) {                       // Wlx_p, layer0 K=32 padded from 3
            int l = j >> 12, e = j & 4095;
            if (l == 0) {
                if (e < 2048) {
                    int col = e >> 5, k = e & 31;
                    float v = (k < 3) ? Wl0[col*67 + k] : 0.f;
                    Wlx_p[e] = bf16r(v);
                }
            } else {
                int col = e >> 6, k = e & 63;
                const float* W = (l == 1) ? Wl1 : Wl2;
                Wlx_p[l*4096 + e] = bf16r(W[col*128 + k]);
            }
            continue;
        }
        j -= 12288;
        if (j < 12288) {                       // Wlh_p
            int l = j >> 12, e = j & 4095;
            int col = e >> 6, k = e & 63;
            float v = (l == 0) ? Wl0[col*67 + 3 + k]
                               : ((l == 1) ? Wl1 : Wl2)[col*128 + 64 + k];
            Wlh_p[l*4096 + e] = bf16r(v);
            continue;
        }
        j -= 12288;
        if (j < 768) {                         // bsum = (b_ih + b_hh) * scale
            int l = j >> 8, col = j & 255;
            const float* bi = (l == 0) ? bih0 : ((l == 1) ? bih1 : bih2);
            const float* bh = (l == 0) ? bhh0 : ((l == 1) ? bhh1 : bhh2);
            float sc = (col >= 128 && col < 192) ? TWOLOG2E : LOG2E;
            bsum[l*256 + col] = (bi[col] + bh[col]) * sc;
            continue;
        }
        j -= 768;
        {                                      // x32: padded bf16 node features [n][32]
            int n = j >> 5, k = j & 31;
            x32[j] = bf16r((k < 3) ? x[n*3 + k] : 0.f);
        }
    }
}

// ---------- fused LSTM-aggregate + combine (+head), MFMA version ----------
// Round-0 geometry (1250 blocks, 4 waves, 1 group/block — cross-block slippage is the
// latency hider; 2-group/block variants measured SLOWER). New in this version:
//  (a) software-pipelined accumulators: step t+1's bias + x@Wih is computed into the
//      ping-pong accumulator AFTER step t's pointwise, so the pointwise chain starts
//      right after the h-MFMAs and the x-MFMAs + gather loads fill the LDS/barrier
//      shadow (x-part is h-independent; previously it sat serially in the acc chain).
//  (b) 7 transcendentals/cell instead of 8: one rcp(P*(1+ef)) yields both sigm(f)=P*R
//      and the i*g denominator (1-eg)*(1+ef)*R.
template<int XKC, int LASTL>
__global__ __launch_bounds__(256, 3)
void lstm_mfma_kernel(const unsigned short* __restrict__ xsrc,  // bf16 rows, stride XKC*32 shorts
                      const int* __restrict__ nbrT,
                      const unsigned short* __restrict__ Wih,   // bf16 [256][XKC*32]
                      const unsigned short* __restrict__ Whh,   // bf16 [256][64]
                      const float* __restrict__ bsum,           // [256] prescaled
                      const unsigned short* __restrict__ Wlx,   // bf16 [64][XKC*32]
                      const unsigned short* __restrict__ Wlh,   // bf16 [64][64]
                      const float* __restrict__ bl,             // [64]
                      const float* __restrict__ W_out,          // [64] (LASTL only)
                      const float* __restrict__ b_out,          // [1]  (LASTL only)
                      void* __restrict__ hout)                  // bf16[n][64] or float[n] (LASTL)
{
    __shared__ unsigned short sA[2][1024];   // h transpose, A-frag rows (swizzled), dbuf
    __shared__ float sRed[64];               // head partial sums (LASTL)

    const int w    = threadIdx.x >> 6;       // 0..3
    const int lane = threadIdx.x & 63;
    const int q    = lane >> 4;
    const int c    = lane & 15;
    const int XS   = XKC * 32;

    const int g = blockIdx.x;
    const int node0 = g * 16;
    const int* nbg = nbrT + g * 512;

    // persistent weight fragments: tile t4 = gate, col = 64*t4 + 16w + c, k = 32kc+8q+j
    short8 fWih[4][XKC];
    short8 fWhh[4][2];
    float  biasv[4];
    #pragma unroll
    for (int t4 = 0; t4 < 4; t4++) {
        int col = 64*t4 + 16*w + c;
        biasv[t4] = bsum[col];
        #pragma unroll
        for (int kc = 0; kc < XKC; kc++)
            fWih[t4][kc] = *(const short8*)(Wih + col*XS + kc*32 + q*8);
        #pragma unroll
        for (int kc = 0; kc < 2; kc++)
            fWhh[t4][kc] = *(const short8*)(Whh + col*64 + kc*32 + q*8);
    }

    float  cst[4] = {0.f, 0.f, 0.f, 0.f};
    short8 hA[2] = {};
    const int u = 16*w + c;

    // prologue: acc for t=0 (bias + x-part), xg <- rows for t=1, idx_nxt <- index t=2
    short8 xg[XKC];
    {
        int idx0 = nbg[c];
        #pragma unroll
        for (int kc = 0; kc < XKC; kc++)
            xg[kc] = *(const short8*)(xsrc + (long)idx0 * XS + kc*32 + q*8);
    }
    floatx4 accA[4], accB[4];
    #pragma unroll
    for (int t4 = 0; t4 < 4; t4++) {
        floatx4 a; a[0] = biasv[t4]; a[1] = biasv[t4]; a[2] = biasv[t4]; a[3] = biasv[t4];
        accA[t4] = a;
    }
    #pragma unroll
    for (int t4 = 0; t4 < 4; t4++)
        #pragma unroll
        for (int kc = 0; kc < XKC; kc++)
            accA[t4] = MF(xg[kc], fWih[t4][kc], accA[t4]);
    {
        int idx1 = nbg[16 + c];
        #pragma unroll
        for (int kc = 0; kc < XKC; kc++)
            xg[kc] = *(const short8*)(xsrc + (long)idx1 * XS + kc*32 + q*8);
    }
    int idx_nxt = nbg[32 + c];

    auto STEP = [&](int t, floatx4 (&cur)[4], floatx4 (&nxt)[4]) {
        // complete step-t gates: h-part only (x-part + bias already in cur)
        if (t > 0) {
            #pragma unroll
            for (int t4 = 0; t4 < 4; t4++) {
                cur[t4] = MF(hA[0], fWhh[t4][0], cur[t4]);
                cur[t4] = MF(hA[1], fWhh[t4][1], cur[t4]);
            }
        }
        // pointwise LSTM cell; lane cells: node m=4q+r, unit u (all 4 gates local)
        unsigned short* sAb = sA[t & 1];
        #pragma unroll
        for (int r = 0; r < 4; r++) {
            float gi = cur[0][r], gf = cur[1][r], gg = cur[2][r], go = cur[3][r];
            float ei = ex2(-gi);
            float ef = ex2(-gf);
            float eo = ex2(-go);
            float eg = ex2(-__builtin_fabsf(gg));
            float P  = (1.f + ei) * (1.f + eg);
            float R  = rcp(P * (1.f + ef));                 // one rcp for f-gate AND i*g
            float iG = __builtin_copysignf(1.f - eg, gg) * ((1.f + ef) * R);
            float cm = fmaf(cst[r], P * R, iG);             // P*R = sigm(gf)
            cst[r] = cm;
            float ec = ex2(-TWOLOG2E * __builtin_fabsf(cm));
            float h  = __builtin_copysignf(1.f - ec, cm) * rcp((1.f + eo) * (1.f + ec));
            int row = (4*q + r) + 16*(u >> 3);
            sAb[rowswz(row)*8 + (u & 7)] = bf16r(h);
        }
        // next step's x-part into the other accumulator; fills the LDS/barrier shadow
        if (t < 31) {
            #pragma unroll
            for (int t4 = 0; t4 < 4; t4++) {
                floatx4 a; a[0] = biasv[t4]; a[1] = biasv[t4]; a[2] = biasv[t4]; a[3] = biasv[t4];
                nxt[t4] = a;
            }
            #pragma unroll
            for (int t4 = 0; t4 < 4; t4++)
                #pragma unroll
                for (int kc = 0; kc < XKC; kc++)
                    nxt[t4] = MF(xg[kc], fWih[t4][kc], nxt[t4]);
            // prefetch rows for t+2 (stays in flight across the lgkm-only barrier)
            #pragma unroll
            for (int kc = 0; kc < XKC; kc++)
                xg[kc] = *(const short8*)(xsrc + (long)idx_nxt * XS + kc*32 + q*8);
            int tn = (t + 3 < 32) ? t + 3 : 31;
            idx_nxt = nbg[tn*16 + c];
        }
        lds_barrier();
        hA[0] = *(const short8*)(sA[t & 1] + rowswz(lane)*8);
        hA[1] = *(const short8*)(sA[t & 1] + 512 + rowswz(lane)*8);
    };

    #pragma unroll 1
    for (int tt = 0; tt < 16; ++tt) {      // 2x unroll: static accA/accB ping-pong
        STEP(2*tt,     accA, accB);
        STEP(2*tt + 1, accB, accA);
    }

    // ---- combine: relu([h_in, agg] @ Wl^T + bl); agg frags = hA (final h) ----
    const int col = u;
    short8 fx[XKC], fh[2];
    float blv = bl[col];
    #pragma unroll
    for (int kc = 0; kc < XKC; kc++)
        fx[kc] = *(const short8*)(Wlx + col*XS + kc*32 + q*8);
    fh[0] = *(const short8*)(Wlh + col*64 + q*8);
    fh[1] = *(const short8*)(Wlh + col*64 + 32 + q*8);
    short8 hin[XKC];
    #pragma unroll
    for (int kc = 0; kc < XKC; kc++)
        hin[kc] = *(const short8*)(xsrc + (long)(node0 + c) * XS + kc*32 + q*8);

    floatx4 a; a[0] = blv; a[1] = blv; a[2] = blv; a[3] = blv;
    #pragma unroll
    for (int kc = 0; kc < XKC; kc++) a = MF(hin[kc], fx[kc], a);
    a = MF(hA[0], fh[0], a);
    a = MF(hA[1], fh[1], a);

    if (!LASTL) {
        #pragma unroll
        for (int r = 0; r < 4; r++)
            ((unsigned short*)hout)[(node0 + 4*q + r) * 64 + col] = bf16r(fmaxf(a[r], 0.f));
    } else {
        // fused head: out[n] = sum_u relu_comb[n][u] * W_out[u] + b_out
        float wo = W_out[col];
        float p[4];
        #pragma unroll
        for (int r = 0; r < 4; r++) p[r] = fmaxf(a[r], 0.f) * wo;
        #pragma unroll
        for (int d = 1; d < 16; d <<= 1) {
            #pragma unroll
            for (int r = 0; r < 4; r++) p[r] += __shfl_xor(p[r], d);
        }
        if (c == 0) {
            #pragma unroll
            for (int r = 0; r < 4; r++) sRed[w*16 + 4*q + r] = p[r];
        }
        lds_barrier();
        if (w == 0 && lane < 16)
            ((float*)hout)[node0 + lane] =
                sRed[lane] + sRed[16 + lane] + sRed[32 + lane] + sRed[48 + lane] + b_out[0];
    }
}

extern "C" void kernel_launch(void* const* d_in, const int* in_sizes, int n_in,
                              void* d_out, int out_size, void* d_ws, size_t ws_size,
                              hipStream_t stream) {
    (void)in_sizes; (void)n_in; (void)out_size; (void)ws_size;
    const float* node_features = (const float*)d_in[0];
    const int*   nbr           = (const int*)d_in[1];
    const float* Wih[3] = {(const float*)d_in[2],  (const float*)d_in[8],  (const float*)d_in[14]};
    const float* Whh[3] = {(const float*)d_in[3],  (const float*)d_in[9],  (const float*)d_in[15]};
    const float* bih[3] = {(const float*)d_in[4],  (const float*)d_in[10], (const float*)d_in[16]};
    const float* bhh[3] = {(const float*)d_in[5],  (const float*)d_in[11], (const float*)d_in[17]};
    const float* Wl[3]  = {(const float*)d_in[6],  (const float*)d_in[12], (const float*)d_in[18]};
    const float* bl[3]  = {(const float*)d_in[7],  (const float*)d_in[13], (const float*)d_in[19]};
    const float* W_out  = (const float*)d_in[20];
    const float* b_out  = (const float*)d_in[21];

    char* ws = (char*)d_ws;
    int*            nbrT  = (int*)ws;                               // 2,560,000 B
    unsigned short* x32   = (unsigned short*)(ws + 2560000);        // 1,280,000 B
    unsigned short* hb1   = (unsigned short*)(ws + 3840000);        // 2,560,000 B
    unsigned short* hb2   = (unsigned short*)(ws + 6400000);        // 2,560,000 B
    unsigned short* Wih_p = (unsigned short*)(ws + 8960000);        // 98,304 B
    unsigned short* Whh_p = (unsigned short*)(ws + 9058304);        // 98,304 B
    unsigned short* Wlx_p = (unsigned short*)(ws + 9156608);        // 24,576 B
    unsigned short* Wlh_p = (unsigned short*)(ws + 9181184);        // 24,576 B
    float*          bsum  = (float*)(ws + 9205760);                 // 3,072 B

    prep_sort_kernel<<<SORT_BLOCKS + PREP_BLOCKS, 256, 0, stream>>>(node_features,
        nbr, nbrT,
        Wih[0], Whh[0], bih[0], bhh[0], Wl[0],
        Wih[1], Whh[1], bih[1], bhh[1], Wl[1],
        Wih[2], Whh[2], bih[2], bhh[2], Wl[2],
        Wih_p, Whh_p, Wlx_p, Wlh_p, bsum, x32);

    lstm_mfma_kernel<1, 0><<<NG, 256, 0, stream>>>(x32, nbrT,
        Wih_p,         Whh_p,         bsum,       Wlx_p,        Wlh_p,        bl[0],
        nullptr, nullptr, hb1);
    lstm_mfma_kernel<2, 0><<<NG, 256, 0, stream>>>(hb1, nbrT,
        Wih_p + 16384, Whh_p + 16384, bsum + 256, Wlx_p + 4096, Wlh_p + 4096, bl[1],
        nullptr, nullptr, hb2);
    lstm_mfma_kernel<2, 1><<<NG, 256, 0, stream>>>(hb2, nbrT,
        Wih_p + 32768, Whh_p + 32768, bsum + 512, Wlx_p + 8192, Wlh_p + 8192, bl[2],
        W_out, b_out, (float*)d_out);
}